// Round 3
// baseline (52906.512 us; speedup 1.0000x reference)
//
#include <hip/hip_runtime.h>
#include <math.h>

// Problem constants
#define TY 128
#define B  64
#define TX 400
#define IN 512
#define H  512
#define C  512
#define NH 8
#define DH 64
#define G4 2048   // 4*H

#define MAXBLK 512

__device__ __forceinline__ float sigf(float x) { return 1.f / (1.f + __expf(-x)); }

// ---------------------------------------------------------------------------
// Generic tiled GEMM (precompute only): Out[r,n] = sum_k A[r,k]*W[n,k] + b1 (+b2)
// ---------------------------------------------------------------------------
__global__ __launch_bounds__(256) void gemm_bias(
    const float* __restrict__ A, const float* __restrict__ W,
    const float* __restrict__ bias1, const float* __restrict__ bias2,
    float* __restrict__ Out, int N, int K) {
  __shared__ float As[16][68];
  __shared__ float Ws[16][68];
  int tid = threadIdx.x;
  int n0 = blockIdx.x * 64;
  int r0 = blockIdx.y * 64;
  int tx = tid & 15, ty = tid >> 4;
  float acc[4][4] = {};
  for (int k0 = 0; k0 < K; k0 += 16) {
    #pragma unroll
    for (int i = 0; i < 4; i++) {
      int idx = tid + i * 256;
      int r = idx >> 4, k = idx & 15;
      As[k][r] = A[(size_t)(r0 + r) * K + k0 + k];
      Ws[k][r] = W[(size_t)(n0 + r) * K + k0 + k];
    }
    __syncthreads();
    #pragma unroll
    for (int k = 0; k < 16; k++) {
      float a[4], w[4];
      #pragma unroll
      for (int i = 0; i < 4; i++) a[i] = As[k][ty * 4 + i];
      #pragma unroll
      for (int j = 0; j < 4; j++) w[j] = Ws[k][tx * 4 + j];
      #pragma unroll
      for (int i = 0; i < 4; i++)
        #pragma unroll
        for (int j = 0; j < 4; j++) acc[i][j] += a[i] * w[j];
    }
    __syncthreads();
  }
  #pragma unroll
  for (int i = 0; i < 4; i++) {
    int r = r0 + ty * 4 + i;
    #pragma unroll
    for (int j = 0; j < 4; j++) {
      int n = n0 + tx * 4 + j;
      float v = acc[i][j];
      if (bias1) v += bias1[n];
      if (bias2) v += bias2[n];
      Out[(size_t)r * N + n] = v;
    }
  }
}

// ---------------------------------------------------------------------------
// Fast hierarchical grid barrier (monotonic epochs; state memset per launch)
// ---------------------------------------------------------------------------
#define BAR_NBUCK  8
#define BAR_STRIDE 32                       // 128 B between counters
#define BAR_ROOT   (BAR_NBUCK * BAR_STRIDE) // 256
#define BAR_EPOCH  (BAR_ROOT + BAR_STRIDE)  // 288
#define BAR_WORDS  (BAR_EPOCH + BAR_STRIDE) // 320 uints

__device__ __forceinline__ void grid_barrier(unsigned* bs, unsigned iter, int nb) {
  __syncthreads();
  if (threadIdx.x == 0) {
    __threadfence();   // agent-scope release: publish this block's writes
    const int bu = (int)blockIdx.x & (BAR_NBUCK - 1);
    const unsigned bsz = (unsigned)(nb >> 3);   // nb is a multiple of 8
    unsigned old = __hip_atomic_fetch_add(bs + bu * BAR_STRIDE, 1u,
                                          __ATOMIC_RELAXED,
                                          __HIP_MEMORY_SCOPE_AGENT);
    if (old == iter * bsz - 1u) {
      unsigned r = __hip_atomic_fetch_add(bs + BAR_ROOT, 1u,
                                          __ATOMIC_RELAXED,
                                          __HIP_MEMORY_SCOPE_AGENT);
      if (r == iter * (unsigned)BAR_NBUCK - 1u) {
        __hip_atomic_store(bs + BAR_EPOCH, iter, __ATOMIC_RELEASE,
                           __HIP_MEMORY_SCOPE_AGENT);
      }
    }
    while (__hip_atomic_load(bs + BAR_EPOCH, __ATOMIC_ACQUIRE,
                             __HIP_MEMORY_SCOPE_AGENT) < iter)
      __builtin_amdgcn_s_sleep(1);
    __threadfence();   // agent-scope acquire: invalidate stale cached lines
  }
  __syncthreads();
}

// ---------------------------------------------------------------------------
// Persistent step kernel
// ---------------------------------------------------------------------------
struct SMem {
  union {
    struct { float As[16][68]; float Ws[16][68]; } g;                     // 8704 B
    struct { float se[400]; float wsh[512]; float sm[4]; float ssum[4];
             float buf[4][64]; } sa;                                      // 4704 B
    struct { float s_att[512]; float s_o[512]; float rs[4]; float rq[4]; } cl;
  } u;
};

struct Params {
  const float *h0, *c0, *x_mask, *y_mask, *init_cov;
  const float *W_hh, *W_comb, *U_att, *W_cov, *W_cat, *ln_g, *ln_b;
  const float *xW, *pctx, *pv;
  float *gatesP, *hqP, *attbuf, *acc0, *acc1;
  float *hs, *cs, *ss, *atts, *dists, *Cs;
  unsigned *bar;
};

// 64-row tile GEMM into slice buffer: rows = 64 batch rows, cols [n0,n0+64),
// K slice [kbeg,kbeg+KS). A row stride fixed at 512 (A1/A2 halves if SPLITA).
template<bool SPLITA>
__device__ __forceinline__ void gemm_tile64(
    const float* __restrict__ A1, const float* __restrict__ A2,
    const float* __restrict__ W, float* __restrict__ Out,
    const int N, const int Ktot, const int kbeg, const int KS,
    const int n0, const int sliceIdx, SMem* sh) {
  const int tid = threadIdx.x;
  const int tx = tid & 15, ty = tid >> 4;
  float acc[4][4] = {};
  for (int k0 = kbeg; k0 < kbeg + KS; k0 += 16) {
    #pragma unroll
    for (int i = 0; i < 4; i++) {
      int idx = tid + i * 256;
      int r = idx >> 4, k = idx & 15;
      int kk = k0 + k;
      float av;
      if constexpr (SPLITA) {
        av = (kk < 512) ? A1[r * 512 + kk] : A2[r * 512 + (kk - 512)];
      } else {
        av = A1[r * 512 + kk];
      }
      sh->u.g.As[k][r] = av;
      sh->u.g.Ws[k][r] = W[(size_t)(n0 + r) * Ktot + kk];
    }
    __syncthreads();
    #pragma unroll
    for (int k = 0; k < 16; k++) {
      float a[4], w[4];
      #pragma unroll
      for (int i = 0; i < 4; i++) a[i] = sh->u.g.As[k][ty * 4 + i];
      #pragma unroll
      for (int j = 0; j < 4; j++) w[j] = sh->u.g.Ws[k][tx * 4 + j];
      #pragma unroll
      for (int i = 0; i < 4; i++)
        #pragma unroll
        for (int j = 0; j < 4; j++) acc[i][j] += a[i] * w[j];
    }
    __syncthreads();
  }
  float* Pp = Out + (size_t)sliceIdx * 64 * N;
  #pragma unroll
  for (int i = 0; i < 4; i++)
    #pragma unroll
    for (int j = 0; j < 4; j++)
      Pp[(size_t)(ty * 4 + i) * N + n0 + tx * 4 + j] = acc[i][j];
}

// One LSTM-cell element (idx in [0, B*H)) for step t.
__device__ __forceinline__ void cell_one(const Params& p, int idx, int t) {
  const float* hp = t ? p.hs + (size_t)(t - 1) * B * H : p.h0;
  const float* cp = t ? p.cs + (size_t)(t - 1) * B * H : p.c0;
  const int b = idx >> 9, m = idx & 511;
  const float* xWt = p.xW + (size_t)t * B * G4;
  float g4[4];
  #pragma unroll
  for (int q = 0; q < 4; q++) {
    int j = q * 512 + m;
    float g = xWt[b * G4 + j];
    #pragma unroll
    for (int s = 0; s < 8; s++) g += p.gatesP[(size_t)(s * 64 + b) * G4 + j];
    g4[q] = g;
  }
  float i_ = sigf(g4[0]);
  float f_ = sigf(g4[1]);
  float gg = tanhf(g4[2]);
  float o_ = sigf(g4[3]);
  float cpv = cp[idx], hpv = hp[idx];
  float c1 = f_ * cpv + i_ * gg;
  float h1 = o_ * tanhf(c1);
  float ym = p.y_mask[t * B + b];
  h1 = ym * h1 + (1.f - ym) * hpv;
  c1 = ym * c1 + (1.f - ym) * cpv;
  p.hs[(size_t)t * B * H + idx] = h1;
  p.ss[(size_t)t * B * H + idx] = h1;
  p.cs[(size_t)t * B * H + idx] = c1;
}

// Fused per-(b,h) unit: [embedded cell(t+1)] + e-scores + softmax + coverage
// + pv-weighted sum. u in [0,512).
__device__ void fused_unit(const Params& p, int u, int t,
                           const float* __restrict__ acc_in,
                           float* __restrict__ acc_out,
                           float* __restrict__ dist_t, float* __restrict__ Cs_t,
                           SMem* sh) {
  const int tid = threadIdx.x, wv = tid >> 6, lane = tid & 63;
  // embedded LSTM cell for step t+1 (gatesP(t+1) was written in P2)
  if (t + 1 < TY && tid < 64) cell_one(p, u * 64 + tid, t + 1);

  const int b = u >> 3, h = u & 7;
  const int c = h * 64 + lane;
  float hqv = 0.f;
  #pragma unroll
  for (int s = 0; s < 8; s++) hqv += p.hqP[(size_t)s * (B * C) + b * C + c];
  const float wcv = p.W_cov[c];
  const float uv = p.U_att[c];

  // e over t' (4 waves split t'; 100 iters each)
  #pragma unroll 4
  for (int q = 0; q < TX / 4; q++) {
    int tt = q * 4 + wv;
    float a = acc_in[b * TX + tt];
    float xm = p.x_mask[tt * B + b];
    float pc = p.pctx[((size_t)(tt * B + b)) * C + c];
    float v = tanhf(pc + hqv + a * wcv) * uv;
    #pragma unroll
    for (int off = 32; off; off >>= 1) v += __shfl_xor(v, off);
    if (lane == 0) sh->u.sa.se[tt] = v * xm;
  }
  __syncthreads();

  // softmax over 400 (threads hold elements tid, tid+256)
  float e0 = (tid < TX) ? sh->u.sa.se[tid] : -1e30f;
  float e1 = (tid + 256 < TX) ? sh->u.sa.se[tid + 256] : -1e30f;
  float m = fmaxf(e0, e1);
  #pragma unroll
  for (int off = 32; off; off >>= 1) m = fmaxf(m, __shfl_xor(m, off));
  if (lane == 0) sh->u.sa.sm[wv] = m;
  __syncthreads();
  m = fmaxf(fmaxf(sh->u.sa.sm[0], sh->u.sa.sm[1]),
            fmaxf(sh->u.sa.sm[2], sh->u.sa.sm[3]));
  float xm0 = (tid < TX) ? p.x_mask[tid * B + b] : 0.f;
  float xm1 = (tid + 256 < TX) ? p.x_mask[(tid + 256) * B + b] : 0.f;
  float w0 = (tid < TX) ? __expf(e0 - m) * xm0 : 0.f;
  float w1 = (tid + 256 < TX) ? __expf(e1 - m) * xm1 : 0.f;
  float s = w0 + w1;
  #pragma unroll
  for (int off = 32; off; off >>= 1) s += __shfl_xor(s, off);
  if (lane == 0) sh->u.sa.ssum[wv] = s;
  __syncthreads();
  s = sh->u.sa.ssum[0] + sh->u.sa.ssum[1] + sh->u.sa.ssum[2] +
      sh->u.sa.ssum[3] + 1e-6f;
  float inv = 1.f / s;
  w0 *= inv; w1 *= inv;
  sh->u.sa.wsh[tid] = w0;
  sh->u.sa.wsh[tid + 256] = w1;
  if (h == 0) {   // coverage / dist / Cs (ping-pong acc: read in, write out)
    if (tid < TX) {
      float a = acc_in[b * TX + tid];
      dist_t[b * TX + tid] = w0;
      Cs_t[b * TX + tid] = a;
      acc_out[b * TX + tid] = a + w0;
    }
    if (tid + 256 < TX) {
      float a = acc_in[b * TX + tid + 256];
      dist_t[b * TX + tid + 256] = w1;
      Cs_t[b * TX + tid + 256] = a;
      acc_out[b * TX + tid + 256] = a + w1;
    }
  }
  __syncthreads();

  // attention-weighted pv sum
  float pacc = 0.f;
  #pragma unroll 4
  for (int tt = wv; tt < TX; tt += 4)
    pacc += sh->u.sa.wsh[tt] * p.pv[((size_t)(tt * 64 + b) * 8 + h) * 64 + lane];
  sh->u.sa.buf[wv][lane] = pacc;
  __syncthreads();
  if (wv == 0)
    p.attbuf[b * 512 + h * 64 + lane] =
        sh->u.sa.buf[0][lane] + sh->u.sa.buf[1][lane] +
        sh->u.sa.buf[2][lane] + sh->u.sa.buf[3][lane];
  __syncthreads();   // LDS reuse guard
}

// att @ W_concat^T + LayerNorm, one unit per b
__device__ __forceinline__ void concat_block(
    int b, const float* __restrict__ att, const float* __restrict__ Wcat,
    const float* __restrict__ ln_g, const float* __restrict__ ln_b,
    float* __restrict__ atts_out, SMem* sh) {
  const int tid = threadIdx.x, wv = tid >> 6, lane = tid & 63;
  sh->u.cl.s_att[tid] = att[b * 512 + tid];
  sh->u.cl.s_att[tid + 256] = att[b * 512 + tid + 256];
  __syncthreads();
  for (int j = wv; j < 512; j += 4) {
    const float* wr = Wcat + (size_t)j * 512;
    float pq = 0.f;
    #pragma unroll
    for (int q = 0; q < 8; q++) pq += sh->u.cl.s_att[q * 64 + lane] * wr[q * 64 + lane];
    #pragma unroll
    for (int off = 32; off; off >>= 1) pq += __shfl_xor(pq, off);
    if (lane == 0) sh->u.cl.s_o[j] = pq;
  }
  __syncthreads();
  float x0 = sh->u.cl.s_o[tid], x1 = sh->u.cl.s_o[tid + 256];
  float sum = x0 + x1, sq = x0 * x0 + x1 * x1;
  #pragma unroll
  for (int off = 32; off; off >>= 1) {
    sum += __shfl_xor(sum, off);
    sq += __shfl_xor(sq, off);
  }
  if (lane == 0) { sh->u.cl.rs[wv] = sum; sh->u.cl.rq[wv] = sq; }
  __syncthreads();
  sum = sh->u.cl.rs[0] + sh->u.cl.rs[1] + sh->u.cl.rs[2] + sh->u.cl.rs[3];
  sq  = sh->u.cl.rq[0] + sh->u.cl.rq[1] + sh->u.cl.rq[2] + sh->u.cl.rq[3];
  float mu = sum * (1.f / 512.f);
  float var = sq * (1.f / 512.f) - mu * mu;
  float rstd = rsqrtf(var + 1e-5f);
  atts_out[b * 512 + tid] = (x0 - mu) * rstd * ln_g[tid] + ln_b[tid];
  atts_out[b * 512 + tid + 256] =
      (x1 - mu) * rstd * ln_g[tid + 256] + ln_b[tid + 256];
  __syncthreads();   // LDS reuse guard
}

__global__ __launch_bounds__(256, 2) void k_steps(Params p) {
  __shared__ SMem sh;
  const int tid = threadIdx.x;
  const int NB = gridDim.x;
  unsigned it = 0;

  // ---- prologue A: coverage init + gatesP(0) from h0
  for (int i = blockIdx.x * 256 + tid; i < B * TX; i += NB * 256)
    p.acc0[i] = p.init_cov[i];
  for (int g = blockIdx.x; g < 256; g += NB)
    gemm_tile64<false>(p.h0, nullptr, p.W_hh, p.gatesP, G4, 512,
                       (g >> 5) * 64, 64, (g & 31) * 64, g >> 5, &sh);
  grid_barrier(p.bar, ++it, NB);

  // ---- prologue B: cell(0)
  for (int i = blockIdx.x * 256 + tid; i < B * H; i += NB * 256)
    cell_one(p, i, 0);
  grid_barrier(p.bar, ++it, NB);

  for (int t = 0; t < TY; t++) {
    const float* hs_t = p.hs + (size_t)t * B * H;
    const float* cs_t = p.cs + (size_t)t * B * H;

    // ---- P2: hqP split-K GEMM [0..63] ; concat+LN(t-1) [64..127] ;
    //          gatesP(t+1) GEMM [128..383]
    for (int u = blockIdx.x; u < 384; u += NB) {
      if (u < 64) {
        gemm_tile64<true>(hs_t, cs_t, p.W_comb, p.hqP, C, 1024,
                          (u >> 3) * 128, 128, (u & 7) * 64, u >> 3, &sh);
      } else if (u < 128) {
        if (t > 0)
          concat_block(u - 64, p.attbuf, p.W_cat, p.ln_g, p.ln_b,
                       p.atts + (size_t)(t - 1) * B * C, &sh);
      } else if (t + 1 < TY) {
        int g = u - 128;
        gemm_tile64<false>(hs_t, nullptr, p.W_hh, p.gatesP, G4, 512,
                           (g >> 5) * 64, 64, (g & 31) * 64, g >> 5, &sh);
      }
    }
    grid_barrier(p.bar, ++it, NB);

    // ---- P3: fused e+softmax+coverage+att (+ embedded cell(t+1))
    const float* acc_in = (t & 1) ? p.acc1 : p.acc0;
    float* acc_out      = (t & 1) ? p.acc0 : p.acc1;
    float* dist_t = p.dists + (size_t)t * B * TX;
    float* Cs_t   = p.Cs + (size_t)t * B * TX;
    for (int u = blockIdx.x; u < 512; u += NB)
      fused_unit(p, u, t, acc_in, acc_out, dist_t, Cs_t, &sh);
    grid_barrier(p.bar, ++it, NB);
  }

  // ---- epilogue: concat+LN of final step
  for (int u = blockIdx.x; u < 64; u += NB)
    concat_block(u, p.attbuf, p.W_cat, p.ln_g, p.ln_b,
                 p.atts + (size_t)(TY - 1) * B * C, &sh);
}

// ---------------------------------------------------------------------------
extern "C" void kernel_launch(void* const* d_in, const int* in_sizes, int n_in,
                              void* d_out, int out_size, void* d_ws, size_t ws_size,
                              hipStream_t stream) {
  const float* y_emb    = (const float*)d_in[0];
  const float* context  = (const float*)d_in[1];
  const float* h0       = (const float*)d_in[2];
  const float* c0       = (const float*)d_in[3];
  const float* x_mask   = (const float*)d_in[4];
  const float* y_mask   = (const float*)d_in[5];
  const float* init_cov = (const float*)d_in[6];
  const float* W_ih     = (const float*)d_in[7];
  const float* W_hh     = (const float*)d_in[8];
  const float* b_ih     = (const float*)d_in[9];
  const float* b_hh     = (const float*)d_in[10];
  const float* Wc_att   = (const float*)d_in[11];
  const float* b_att    = (const float*)d_in[12];
  const float* Wv_att   = (const float*)d_in[13];
  const float* bv_att   = (const float*)d_in[14];
  const float* W_comb   = (const float*)d_in[15];
  const float* U_att    = (const float*)d_in[16];
  const float* W_cov    = (const float*)d_in[17];
  const float* W_cat    = (const float*)d_in[18];
  const float* ln_g     = (const float*)d_in[19];
  const float* ln_b     = (const float*)d_in[20];

  float* out = (float*)d_out;
  const size_t SZ_H = (size_t)TY * B * H;
  const size_t SZ_D = (size_t)TY * B * TX;
  float* hs    = out;
  float* cs    = out + SZ_H;
  float* ss    = out + 2 * SZ_H;
  float* atts  = out + 3 * SZ_H;
  float* dists = out + 4 * SZ_H;
  float* Cs    = out + 4 * SZ_H + SZ_D;

  float* ws = (float*)d_ws;
  size_t off = 0;
  float* pctx   = ws + off; off += (size_t)TX * B * C;
  float* pv     = ws + off; off += (size_t)TX * B * C;
  float* xW     = ws + off; off += (size_t)TY * B * G4;
  float* gatesP = ws + off; off += (size_t)8 * B * G4;
  float* hqP    = ws + off; off += (size_t)8 * B * C;
  float* attbuf = ws + off; off += (size_t)B * C;
  float* acc0   = ws + off; off += (size_t)B * TX;
  float* acc1   = ws + off; off += (size_t)B * TX;
  unsigned* bar = (unsigned*)(ws + off); off += BAR_WORDS;

  // ---- grid size the cooperative launch is guaranteed to accept
  static int g_nblk = 0;
  if (g_nblk == 0) {
    int maxPerCU = 0;
    if (hipOccupancyMaxActiveBlocksPerMultiprocessor(&maxPerCU, k_steps, 256, 0)
            != hipSuccess || maxPerCU < 1)
      maxPerCU = 1;
    int nCU = 256;
    hipDeviceProp_t prop;
    int dev = 0;
    if (hipGetDevice(&dev) == hipSuccess &&
        hipGetDeviceProperties(&prop, dev) == hipSuccess)
      nCU = prop.multiProcessorCount;
    int nb = maxPerCU * nCU;
    if (nb > MAXBLK) nb = MAXBLK;
    nb &= ~7;                      // barrier assumes multiple of 8
    if (nb < 8) nb = 8;
    g_nblk = nb;
  }

  // ---- barrier state must start zeroed every call (epochs are per-launch)
  hipMemsetAsync(bar, 0, BAR_WORDS * sizeof(unsigned), stream);

  // ---- precompute (big parallel GEMMs, regular launches) ----
  gemm_bias<<<dim3(C / 64, TX * B / 64), 256, 0, stream>>>(
      context, Wc_att, b_att, nullptr, pctx, C, C);
  gemm_bias<<<dim3(C / 64, TX * B / 64), 256, 0, stream>>>(
      context, Wv_att, bv_att, nullptr, pv, C, C);
  gemm_bias<<<dim3(G4 / 64, TY * B / 64), 256, 0, stream>>>(
      y_emb, W_ih, b_ih, b_hh, xW, G4, IN);

  // ---- persistent cooperative kernel for all 128 steps ----
  Params prm;
  prm.h0 = h0; prm.c0 = c0; prm.x_mask = x_mask; prm.y_mask = y_mask;
  prm.init_cov = init_cov;
  prm.W_hh = W_hh; prm.W_comb = W_comb; prm.U_att = U_att; prm.W_cov = W_cov;
  prm.W_cat = W_cat; prm.ln_g = ln_g; prm.ln_b = ln_b;
  prm.xW = xW; prm.pctx = pctx; prm.pv = pv;
  prm.gatesP = gatesP; prm.hqP = hqP; prm.attbuf = attbuf;
  prm.acc0 = acc0; prm.acc1 = acc1;
  prm.hs = hs; prm.cs = cs; prm.ss = ss;
  prm.atts = atts; prm.dists = dists; prm.Cs = Cs;
  prm.bar = bar;

  void* kargs[] = { (void*)&prm };
  hipLaunchCooperativeKernel((void*)k_steps, dim3(g_nblk), dim3(256), kargs, 0,
                             stream);
}

// Round 4
// 18260.098 us; speedup vs baseline: 2.8974x; 2.8974x over previous
//
#include <hip/hip_runtime.h>
#include <math.h>

// Problem constants
#define TY 128
#define B  64
#define TX 400
#define IN 512
#define H  512
#define C  512
#define NH 8
#define DH 64
#define G4 2048   // 4*H

__device__ __forceinline__ float sigf(float x) { return 1.f / (1.f + __expf(-x)); }

// ---------------------------------------------------------------------------
// Generic tiled GEMM (precompute only): Out[r,n] = sum_k A[r,k]*W[n,k] + b1 (+b2)
// ---------------------------------------------------------------------------
__global__ __launch_bounds__(256) void gemm_bias(
    const float* __restrict__ A, const float* __restrict__ W,
    const float* __restrict__ bias1, const float* __restrict__ bias2,
    float* __restrict__ Out, int N, int K) {
  __shared__ float As[16][68];
  __shared__ float Ws[16][68];
  int tid = threadIdx.x;
  int n0 = blockIdx.x * 64;
  int r0 = blockIdx.y * 64;
  int tx = tid & 15, ty = tid >> 4;
  float acc[4][4] = {};
  for (int k0 = 0; k0 < K; k0 += 16) {
    #pragma unroll
    for (int i = 0; i < 4; i++) {
      int idx = tid + i * 256;
      int r = idx >> 4, k = idx & 15;
      As[k][r] = A[(size_t)(r0 + r) * K + k0 + k];
      Ws[k][r] = W[(size_t)(n0 + r) * K + k0 + k];
    }
    __syncthreads();
    #pragma unroll
    for (int k = 0; k < 16; k++) {
      float a[4], w[4];
      #pragma unroll
      for (int i = 0; i < 4; i++) a[i] = As[k][ty * 4 + i];
      #pragma unroll
      for (int j = 0; j < 4; j++) w[j] = Ws[k][tx * 4 + j];
      #pragma unroll
      for (int i = 0; i < 4; i++)
        #pragma unroll
        for (int j = 0; j < 4; j++) acc[i][j] += a[i] * w[j];
    }
    __syncthreads();
  }
  #pragma unroll
  for (int i = 0; i < 4; i++) {
    int r = r0 + ty * 4 + i;
    #pragma unroll
    for (int j = 0; j < 4; j++) {
      int n = n0 + tx * 4 + j;
      float v = acc[i][j];
      if (bias1) v += bias1[n];
      if (bias2) v += bias2[n];
      Out[(size_t)r * N + n] = v;
    }
  }
}

// ---------------------------------------------------------------------------
struct SMem {
  union {
    struct { float As[16][68]; float Ws[16][68]; } g;                     // 8704 B
    struct { float se[400]; float wsh[512]; float sm[4]; float ssum[4];
             float buf[4][64]; } sa;
    struct { float s_att[512]; float s_o[512]; float rs[4]; float rq[4]; } cl;
  } u;
};

struct Params {
  const float *h0, *c0, *x_mask, *y_mask, *init_cov;
  const float *W_hh, *W_comb, *U_att, *W_cov, *W_cat, *ln_g, *ln_b;
  const float *xW, *pctx, *pv;
  float *gatesP, *hqP, *attbuf, *acc0, *acc1;
  float *hs, *cs, *ss, *atts, *dists, *Cs;
};

// 64-row tile GEMM into slice buffer: rows = 64 batch rows, cols [n0,n0+64),
// K slice [kbeg,kbeg+KS). A row stride fixed at 512 (A1/A2 halves if SPLITA).
template<bool SPLITA>
__device__ __forceinline__ void gemm_tile64(
    const float* __restrict__ A1, const float* __restrict__ A2,
    const float* __restrict__ W, float* __restrict__ Out,
    const int N, const int Ktot, const int kbeg, const int KS,
    const int n0, const int sliceIdx, SMem* sh) {
  const int tid = threadIdx.x;
  const int tx = tid & 15, ty = tid >> 4;
  float acc[4][4] = {};
  for (int k0 = kbeg; k0 < kbeg + KS; k0 += 16) {
    #pragma unroll
    for (int i = 0; i < 4; i++) {
      int idx = tid + i * 256;
      int r = idx >> 4, k = idx & 15;
      int kk = k0 + k;
      float av;
      if constexpr (SPLITA) {
        av = (kk < 512) ? A1[r * 512 + kk] : A2[r * 512 + (kk - 512)];
      } else {
        av = A1[r * 512 + kk];
      }
      sh->u.g.As[k][r] = av;
      sh->u.g.Ws[k][r] = W[(size_t)(n0 + r) * Ktot + kk];
    }
    __syncthreads();
    #pragma unroll
    for (int k = 0; k < 16; k++) {
      float a[4], w[4];
      #pragma unroll
      for (int i = 0; i < 4; i++) a[i] = sh->u.g.As[k][ty * 4 + i];
      #pragma unroll
      for (int j = 0; j < 4; j++) w[j] = sh->u.g.Ws[k][tx * 4 + j];
      #pragma unroll
      for (int i = 0; i < 4; i++)
        #pragma unroll
        for (int j = 0; j < 4; j++) acc[i][j] += a[i] * w[j];
    }
    __syncthreads();
  }
  float* Pp = Out + (size_t)sliceIdx * 64 * N;
  #pragma unroll
  for (int i = 0; i < 4; i++)
    #pragma unroll
    for (int j = 0; j < 4; j++)
      Pp[(size_t)(ty * 4 + i) * N + n0 + tx * 4 + j] = acc[i][j];
}

// One LSTM-cell element (idx in [0, B*H)) for step t.
__device__ __forceinline__ void cell_one(const Params& p, int idx, int t) {
  const float* hp = t ? p.hs + (size_t)(t - 1) * B * H : p.h0;
  const float* cp = t ? p.cs + (size_t)(t - 1) * B * H : p.c0;
  const int b = idx >> 9, m = idx & 511;
  const float* xWt = p.xW + (size_t)t * B * G4;
  float g4[4];
  #pragma unroll
  for (int q = 0; q < 4; q++) {
    int j = q * 512 + m;
    float g = xWt[b * G4 + j];
    #pragma unroll
    for (int s = 0; s < 8; s++) g += p.gatesP[(size_t)(s * 64 + b) * G4 + j];
    g4[q] = g;
  }
  float i_ = sigf(g4[0]);
  float f_ = sigf(g4[1]);
  float gg = tanhf(g4[2]);
  float o_ = sigf(g4[3]);
  float cpv = cp[idx], hpv = hp[idx];
  float c1 = f_ * cpv + i_ * gg;
  float h1 = o_ * tanhf(c1);
  float ym = p.y_mask[t * B + b];
  h1 = ym * h1 + (1.f - ym) * hpv;
  c1 = ym * c1 + (1.f - ym) * cpv;
  p.hs[(size_t)t * B * H + idx] = h1;
  p.ss[(size_t)t * B * H + idx] = h1;
  p.cs[(size_t)t * B * H + idx] = c1;
}

// Fused per-(b,h) unit: [embedded cell(t+1)] + hq-reduce + e-scores + softmax
// + coverage + pv-weighted sum. u in [0,512).
__device__ void fused_unit(const Params& p, int u, int t,
                           const float* __restrict__ acc_in,
                           float* __restrict__ acc_out,
                           float* __restrict__ dist_t, float* __restrict__ Cs_t,
                           SMem* sh) {
  const int tid = threadIdx.x, wv = tid >> 6, lane = tid & 63;
  // embedded LSTM cell for step t+1 (gatesP(t+1) was written in phase 1)
  if (t + 1 < TY && tid < 64) cell_one(p, u * 64 + tid, t + 1);

  const int b = u >> 3, h = u & 7;
  const int c = h * 64 + lane;
  float hqv = 0.f;
  #pragma unroll
  for (int s = 0; s < 8; s++) hqv += p.hqP[(size_t)s * (B * C) + b * C + c];
  const float wcv = p.W_cov[c];
  const float uv = p.U_att[c];

  // e over t' (4 waves split t'; 100 iters each)
  #pragma unroll 4
  for (int q = 0; q < TX / 4; q++) {
    int tt = q * 4 + wv;
    float a = acc_in[b * TX + tt];
    float xm = p.x_mask[tt * B + b];
    float pc = p.pctx[((size_t)(tt * B + b)) * C + c];
    float v = tanhf(pc + hqv + a * wcv) * uv;
    #pragma unroll
    for (int off = 32; off; off >>= 1) v += __shfl_xor(v, off);
    if (lane == 0) sh->u.sa.se[tt] = v * xm;
  }
  __syncthreads();

  // softmax over 400 (threads hold elements tid, tid+256)
  float e0 = (tid < TX) ? sh->u.sa.se[tid] : -1e30f;
  float e1 = (tid + 256 < TX) ? sh->u.sa.se[tid + 256] : -1e30f;
  float m = fmaxf(e0, e1);
  #pragma unroll
  for (int off = 32; off; off >>= 1) m = fmaxf(m, __shfl_xor(m, off));
  if (lane == 0) sh->u.sa.sm[wv] = m;
  __syncthreads();
  m = fmaxf(fmaxf(sh->u.sa.sm[0], sh->u.sa.sm[1]),
            fmaxf(sh->u.sa.sm[2], sh->u.sa.sm[3]));
  float xm0 = (tid < TX) ? p.x_mask[tid * B + b] : 0.f;
  float xm1 = (tid + 256 < TX) ? p.x_mask[(tid + 256) * B + b] : 0.f;
  float w0 = (tid < TX) ? __expf(e0 - m) * xm0 : 0.f;
  float w1 = (tid + 256 < TX) ? __expf(e1 - m) * xm1 : 0.f;
  float s = w0 + w1;
  #pragma unroll
  for (int off = 32; off; off >>= 1) s += __shfl_xor(s, off);
  if (lane == 0) sh->u.sa.ssum[wv] = s;
  __syncthreads();
  s = sh->u.sa.ssum[0] + sh->u.sa.ssum[1] + sh->u.sa.ssum[2] +
      sh->u.sa.ssum[3] + 1e-6f;
  float inv = 1.f / s;
  w0 *= inv; w1 *= inv;
  sh->u.sa.wsh[tid] = w0;
  sh->u.sa.wsh[tid + 256] = w1;
  if (h == 0) {   // coverage / dist / Cs (ping-pong acc: read in, write out)
    if (tid < TX) {
      float a = acc_in[b * TX + tid];
      dist_t[b * TX + tid] = w0;
      Cs_t[b * TX + tid] = a;
      acc_out[b * TX + tid] = a + w0;
    }
    if (tid + 256 < TX) {
      float a = acc_in[b * TX + tid + 256];
      dist_t[b * TX + tid + 256] = w1;
      Cs_t[b * TX + tid + 256] = a;
      acc_out[b * TX + tid + 256] = a + w1;
    }
  }
  __syncthreads();

  // attention-weighted pv sum
  float pacc = 0.f;
  #pragma unroll 4
  for (int tt = wv; tt < TX; tt += 4)
    pacc += sh->u.sa.wsh[tt] * p.pv[((size_t)(tt * 64 + b) * 8 + h) * 64 + lane];
  sh->u.sa.buf[wv][lane] = pacc;
  __syncthreads();
  if (wv == 0)
    p.attbuf[b * 512 + h * 64 + lane] =
        sh->u.sa.buf[0][lane] + sh->u.sa.buf[1][lane] +
        sh->u.sa.buf[2][lane] + sh->u.sa.buf[3][lane];
}

// att @ W_concat^T + LayerNorm, one unit per b
__device__ __forceinline__ void concat_block(
    int b, const float* __restrict__ att, const float* __restrict__ Wcat,
    const float* __restrict__ ln_g, const float* __restrict__ ln_b,
    float* __restrict__ atts_out, SMem* sh) {
  const int tid = threadIdx.x, wv = tid >> 6, lane = tid & 63;
  sh->u.cl.s_att[tid] = att[b * 512 + tid];
  sh->u.cl.s_att[tid + 256] = att[b * 512 + tid + 256];
  __syncthreads();
  for (int j = wv; j < 512; j += 4) {
    const float* wr = Wcat + (size_t)j * 512;
    float pq = 0.f;
    #pragma unroll
    for (int q = 0; q < 8; q++) pq += sh->u.cl.s_att[q * 64 + lane] * wr[q * 64 + lane];
    #pragma unroll
    for (int off = 32; off; off >>= 1) pq += __shfl_xor(pq, off);
    if (lane == 0) sh->u.cl.s_o[j] = pq;
  }
  __syncthreads();
  float x0 = sh->u.cl.s_o[tid], x1 = sh->u.cl.s_o[tid + 256];
  float sum = x0 + x1, sq = x0 * x0 + x1 * x1;
  #pragma unroll
  for (int off = 32; off; off >>= 1) {
    sum += __shfl_xor(sum, off);
    sq += __shfl_xor(sq, off);
  }
  if (lane == 0) { sh->u.cl.rs[wv] = sum; sh->u.cl.rq[wv] = sq; }
  __syncthreads();
  sum = sh->u.cl.rs[0] + sh->u.cl.rs[1] + sh->u.cl.rs[2] + sh->u.cl.rs[3];
  sq  = sh->u.cl.rq[0] + sh->u.cl.rq[1] + sh->u.cl.rq[2] + sh->u.cl.rq[3];
  float mu = sum * (1.f / 512.f);
  float var = sq * (1.f / 512.f) - mu * mu;
  float rstd = rsqrtf(var + 1e-5f);
  atts_out[b * 512 + tid] = (x0 - mu) * rstd * ln_g[tid] + ln_b[tid];
  atts_out[b * 512 + tid + 256] =
      (x1 - mu) * rstd * ln_g[tid + 256] + ln_b[tid + 256];
}

// ---------------------------------------------------------------------------
// Step kernels (2 launches per step, heterogeneous block roles)
// ---------------------------------------------------------------------------

// Prologue: gates(0) from h0 [blocks 0..255] ; acc0 <- init_cov [256..355]
__global__ __launch_bounds__(256) void k_prolog(Params p) {
  __shared__ SMem sh;
  int u = blockIdx.x;
  if (u < 256) {
    gemm_tile64<false>(p.h0, nullptr, p.W_hh, p.gatesP, G4, 512,
                       (u >> 5) * 64, 64, (u & 31) * 64, u >> 5, &sh);
  } else {
    int i = (u - 256) * 256 + threadIdx.x;
    if (i < B * TX) p.acc0[i] = p.init_cov[i];
  }
}

// cell(0): 128 blocks
__global__ __launch_bounds__(256) void k_cell0(Params p) {
  cell_one(p, blockIdx.x * 256 + threadIdx.x, 0);
}

// Phase 1: hqP split-K GEMM [0..63] ; concat+LN(t-1) [64..127] ;
//          gates(t+1) GEMM [128..383]
__global__ __launch_bounds__(256) void k_phase1(Params p, int t) {
  __shared__ SMem sh;
  const int u = blockIdx.x;
  const float* hs_t = p.hs + (size_t)t * B * H;
  const float* cs_t = p.cs + (size_t)t * B * H;
  if (u < 64) {
    gemm_tile64<true>(hs_t, cs_t, p.W_comb, p.hqP, C, 1024,
                      (u >> 3) * 128, 128, (u & 7) * 64, u >> 3, &sh);
  } else if (u < 128) {
    if (t > 0)
      concat_block(u - 64, p.attbuf, p.W_cat, p.ln_g, p.ln_b,
                   p.atts + (size_t)(t - 1) * B * C, &sh);
  } else if (t + 1 < TY) {
    int g = u - 128;
    gemm_tile64<false>(hs_t, nullptr, p.W_hh, p.gatesP, G4, 512,
                       (g >> 5) * 64, 64, (g & 31) * 64, g >> 5, &sh);
  }
}

// Phase 2: fused attention (+ embedded cell(t+1)), 512 blocks
__global__ __launch_bounds__(256) void k_phase2(Params p, int t) {
  __shared__ SMem sh;
  const float* acc_in = (t & 1) ? p.acc1 : p.acc0;
  float* acc_out      = (t & 1) ? p.acc0 : p.acc1;
  fused_unit(p, blockIdx.x, t, acc_in, acc_out,
             p.dists + (size_t)t * B * TX, p.Cs + (size_t)t * B * TX, &sh);
}

// Epilogue: concat+LN of final step, 64 blocks
__global__ __launch_bounds__(256) void k_epilog(Params p) {
  __shared__ SMem sh;
  concat_block(blockIdx.x, p.attbuf, p.W_cat, p.ln_g, p.ln_b,
               p.atts + (size_t)(TY - 1) * B * C, &sh);
}

// ---------------------------------------------------------------------------
extern "C" void kernel_launch(void* const* d_in, const int* in_sizes, int n_in,
                              void* d_out, int out_size, void* d_ws, size_t ws_size,
                              hipStream_t stream) {
  const float* y_emb    = (const float*)d_in[0];
  const float* context  = (const float*)d_in[1];
  const float* h0       = (const float*)d_in[2];
  const float* c0       = (const float*)d_in[3];
  const float* x_mask   = (const float*)d_in[4];
  const float* y_mask   = (const float*)d_in[5];
  const float* init_cov = (const float*)d_in[6];
  const float* W_ih     = (const float*)d_in[7];
  const float* W_hh     = (const float*)d_in[8];
  const float* b_ih     = (const float*)d_in[9];
  const float* b_hh     = (const float*)d_in[10];
  const float* Wc_att   = (const float*)d_in[11];
  const float* b_att    = (const float*)d_in[12];
  const float* Wv_att   = (const float*)d_in[13];
  const float* bv_att   = (const float*)d_in[14];
  const float* W_comb   = (const float*)d_in[15];
  const float* U_att    = (const float*)d_in[16];
  const float* W_cov    = (const float*)d_in[17];
  const float* W_cat    = (const float*)d_in[18];
  const float* ln_g     = (const float*)d_in[19];
  const float* ln_b     = (const float*)d_in[20];

  float* out = (float*)d_out;
  const size_t SZ_H = (size_t)TY * B * H;
  const size_t SZ_D = (size_t)TY * B * TX;
  float* hs    = out;
  float* cs    = out + SZ_H;
  float* ss    = out + 2 * SZ_H;
  float* atts  = out + 3 * SZ_H;
  float* dists = out + 4 * SZ_H;
  float* Cs    = out + 4 * SZ_H + SZ_D;

  float* ws = (float*)d_ws;
  size_t off = 0;
  float* pctx   = ws + off; off += (size_t)TX * B * C;
  float* pv     = ws + off; off += (size_t)TX * B * C;
  float* xW     = ws + off; off += (size_t)TY * B * G4;
  float* gatesP = ws + off; off += (size_t)8 * B * G4;
  float* hqP    = ws + off; off += (size_t)8 * B * C;
  float* attbuf = ws + off; off += (size_t)B * C;
  float* acc0   = ws + off; off += (size_t)B * TX;
  float* acc1   = ws + off; off += (size_t)B * TX;

  // ---- precompute (big parallel GEMMs) ----
  gemm_bias<<<dim3(C / 64, TX * B / 64), 256, 0, stream>>>(
      context, Wc_att, b_att, nullptr, pctx, C, C);
  gemm_bias<<<dim3(C / 64, TX * B / 64), 256, 0, stream>>>(
      context, Wv_att, bv_att, nullptr, pv, C, C);
  gemm_bias<<<dim3(G4 / 64, TY * B / 64), 256, 0, stream>>>(
      y_emb, W_ih, b_ih, b_hh, xW, G4, IN);

  Params prm;
  prm.h0 = h0; prm.c0 = c0; prm.x_mask = x_mask; prm.y_mask = y_mask;
  prm.init_cov = init_cov;
  prm.W_hh = W_hh; prm.W_comb = W_comb; prm.U_att = U_att; prm.W_cov = W_cov;
  prm.W_cat = W_cat; prm.ln_g = ln_g; prm.ln_b = ln_b;
  prm.xW = xW; prm.pctx = pctx; prm.pv = pv;
  prm.gatesP = gatesP; prm.hqP = hqP; prm.attbuf = attbuf;
  prm.acc0 = acc0; prm.acc1 = acc1;
  prm.hs = hs; prm.cs = cs; prm.ss = ss;
  prm.atts = atts; prm.dists = dists; prm.Cs = Cs;

  // ---- prologue: gates(0) + coverage init, then cell(0) ----
  k_prolog<<<356, 256, 0, stream>>>(prm);
  k_cell0<<<128, 256, 0, stream>>>(prm);

  // ---- 2 launches per step ----
  for (int t = 0; t < TY; t++) {
    k_phase1<<<384, 256, 0, stream>>>(prm, t);
    k_phase2<<<512, 256, 0, stream>>>(prm, t);
  }
  k_epilog<<<64, 256, 0, stream>>>(prm);
}

// Round 6
// 14418.498 us; speedup vs baseline: 3.6693x; 1.2664x over previous
//
#include <hip/hip_runtime.h>
#include <math.h>

// Problem constants
#define TY 128
#define B  64
#define TX 400
#define IN 512
#define H  512
#define C  512
#define NH 8
#define DH 64
#define G4 2048   // 4*H

__device__ __forceinline__ float sigf(float x) { return 1.f / (1.f + __expf(-x)); }

// ---------------------------------------------------------------------------
// Generic tiled GEMM (precompute only): Out[r,n] = sum_k A[r,k]*W[n,k] + b1 (+b2)
// ---------------------------------------------------------------------------
__global__ __launch_bounds__(256) void gemm_bias(
    const float* __restrict__ A, const float* __restrict__ W,
    const float* __restrict__ bias1, const float* __restrict__ bias2,
    float* __restrict__ Out, int N, int K) {
  __shared__ float As[16][68];
  __shared__ float Ws[16][68];
  int tid = threadIdx.x;
  int n0 = blockIdx.x * 64;
  int r0 = blockIdx.y * 64;
  int tx = tid & 15, ty = tid >> 4;
  float acc[4][4] = {};
  for (int k0 = 0; k0 < K; k0 += 16) {
    #pragma unroll
    for (int i = 0; i < 4; i++) {
      int idx = tid + i * 256;
      int r = idx >> 4, k = idx & 15;
      As[k][r] = A[(size_t)(r0 + r) * K + k0 + k];
      Ws[k][r] = W[(size_t)(n0 + r) * K + k0 + k];
    }
    __syncthreads();
    #pragma unroll
    for (int k = 0; k < 16; k++) {
      float a[4], w[4];
      #pragma unroll
      for (int i = 0; i < 4; i++) a[i] = As[k][ty * 4 + i];
      #pragma unroll
      for (int j = 0; j < 4; j++) w[j] = Ws[k][tx * 4 + j];
      #pragma unroll
      for (int i = 0; i < 4; i++)
        #pragma unroll
        for (int j = 0; j < 4; j++) acc[i][j] += a[i] * w[j];
    }
    __syncthreads();
  }
  #pragma unroll
  for (int i = 0; i < 4; i++) {
    int r = r0 + ty * 4 + i;
    #pragma unroll
    for (int j = 0; j < 4; j++) {
      int n = n0 + tx * 4 + j;
      float v = acc[i][j];
      if (bias1) v += bias1[n];
      if (bias2) v += bias2[n];
      Out[(size_t)r * N + n] = v;
    }
  }
}

// ---------------------------------------------------------------------------
struct SMem {
  union {
    struct { float As[16][68]; float Ws[16][68]; } g;            // prologue GEMM
    struct { float As64[64][65]; float Ws[16][68]; } g2;         // in-step gates GEMM
    struct { float xs[1024];        // [h1(0..511), c1(0..511)] for this b
             float hqp[4][64];      // hq partials (k-quarter x c)
             float hqs[64];         // hq slice for this (b,h)
             float se[400];         // e scores
             float wsh[512];        // softmax weights
             float sm[4]; float ssum[4];
             float pbuf[256]; } at; // pv partials [wv][64]
    struct { float s_att[512]; float s_o[512]; float rs[4]; float rq[4]; } cl;
  } u;
};

struct Params {
  const float *h0, *c0, *x_mask, *y_mask, *init_cov;
  const float *W_hh, *W_comb, *U_att, *W_cov, *W_cat, *ln_g, *ln_b;
  const float *xW, *pctx, *pv;
  float *gates0, *gates1, *att0, *att1, *acc0, *acc1;
  float *hs, *cs, *ss, *atts, *dists, *Cs;
};

// 64-row tile GEMM (prologue): rows = 64 batch rows of A (stride 512),
// cols [n0,n0+64), K slice [kbeg,kbeg+64). Out slice layout [slice][64][N].
__device__ __forceinline__ void gemm_tile64(
    const float* __restrict__ A1, const float* __restrict__ W,
    float* __restrict__ Out, const int N, const int kbeg,
    const int n0, const int sliceIdx, SMem* sh) {
  const int tid = threadIdx.x;
  const int tx = tid & 15, ty = tid >> 4;
  float acc[4][4] = {};
  for (int k0 = kbeg; k0 < kbeg + 64; k0 += 16) {
    #pragma unroll
    for (int i = 0; i < 4; i++) {
      int idx = tid + i * 256;
      int r = idx >> 4, k = idx & 15;
      sh->u.g.As[k][r] = A1[r * 512 + k0 + k];
      sh->u.g.Ws[k][r] = W[(size_t)(n0 + r) * 512 + k0 + k];
    }
    __syncthreads();
    #pragma unroll
    for (int k = 0; k < 16; k++) {
      float a[4], w[4];
      #pragma unroll
      for (int i = 0; i < 4; i++) a[i] = sh->u.g.As[k][ty * 4 + i];
      #pragma unroll
      for (int j = 0; j < 4; j++) w[j] = sh->u.g.Ws[k][tx * 4 + j];
      #pragma unroll
      for (int i = 0; i < 4; i++)
        #pragma unroll
        for (int j = 0; j < 4; j++) acc[i][j] += a[i] * w[j];
    }
    __syncthreads();
  }
  float* Pp = Out + (size_t)sliceIdx * 64 * N;
  #pragma unroll
  for (int i = 0; i < 4; i++)
    #pragma unroll
    for (int j = 0; j < 4; j++)
      Pp[(size_t)(ty * 4 + i) * N + n0 + tx * 4 + j] = acc[i][j];
}

// Compute one cell element for (b,col) at step t; returns h1 (and c1 via ref).
__device__ __forceinline__ float cell_elem(const Params& p,
                                           const float* __restrict__ gates_cur,
                                           int t, int b, int col, float ym,
                                           float& c1_out) {
  const float* xWt = p.xW + (size_t)t * B * G4 + (size_t)b * G4;
  float g4[4];
  #pragma unroll
  for (int q = 0; q < 4; q++) {
    int j = q * 512 + col;
    float g = xWt[j];
    #pragma unroll
    for (int s = 0; s < 8; s++) g += gates_cur[(size_t)(s * 64 + b) * G4 + j];
    g4[q] = g;
  }
  float i_ = sigf(g4[0]);
  float f_ = sigf(g4[1]);
  float gg = tanhf(g4[2]);
  float o_ = sigf(g4[3]);
  float hpv = t ? p.hs[(size_t)(t - 1) * B * H + b * H + col] : p.h0[b * H + col];
  float cpv = t ? p.cs[(size_t)(t - 1) * B * H + b * H + col] : p.c0[b * H + col];
  float c1 = f_ * cpv + i_ * gg;
  float h1 = o_ * tanhf(c1);
  h1 = ym * h1 + (1.f - ym) * hpv;
  c1 = ym * c1 + (1.f - ym) * cpv;
  c1_out = c1;
  return h1;
}

// att @ W_concat^T + LayerNorm, one unit per b
__device__ __forceinline__ void concat_block(
    int b, const float* __restrict__ att, const float* __restrict__ Wcat,
    const float* __restrict__ ln_g, const float* __restrict__ ln_b,
    float* __restrict__ atts_out, SMem* sh) {
  const int tid = threadIdx.x, wv = tid >> 6, lane = tid & 63;
  sh->u.cl.s_att[tid] = att[b * 512 + tid];
  sh->u.cl.s_att[tid + 256] = att[b * 512 + tid + 256];
  __syncthreads();
  for (int j = wv; j < 512; j += 4) {
    const float* wr = Wcat + (size_t)j * 512;
    float pq = 0.f;
    #pragma unroll
    for (int q = 0; q < 8; q++) pq += sh->u.cl.s_att[q * 64 + lane] * wr[q * 64 + lane];
    #pragma unroll
    for (int off = 32; off; off >>= 1) pq += __shfl_xor(pq, off);
    if (lane == 0) sh->u.cl.s_o[j] = pq;
  }
  __syncthreads();
  float x0 = sh->u.cl.s_o[tid], x1 = sh->u.cl.s_o[tid + 256];
  float sum = x0 + x1, sq = x0 * x0 + x1 * x1;
  #pragma unroll
  for (int off = 32; off; off >>= 1) {
    sum += __shfl_xor(sum, off);
    sq += __shfl_xor(sq, off);
  }
  if (lane == 0) { sh->u.cl.rs[wv] = sum; sh->u.cl.rq[wv] = sq; }
  __syncthreads();
  sum = sh->u.cl.rs[0] + sh->u.cl.rs[1] + sh->u.cl.rs[2] + sh->u.cl.rs[3];
  sq  = sh->u.cl.rq[0] + sh->u.cl.rq[1] + sh->u.cl.rq[2] + sh->u.cl.rq[3];
  float mu = sum * (1.f / 512.f);
  float var = sq * (1.f / 512.f) - mu * mu;
  float rstd = rsqrtf(var + 1e-5f);
  atts_out[b * 512 + tid] = (x0 - mu) * rstd * ln_g[tid] + ln_b[tid];
  atts_out[b * 512 + tid + 256] =
      (x1 - mu) * rstd * ln_g[tid + 256] + ln_b[tid + 256];
}

// ---------------------------------------------------------------------------
// Prologue: gates(0) from h0 [blocks 0..255] ; acc0 <- init_cov [256..355]
// ---------------------------------------------------------------------------
__global__ __launch_bounds__(256) void k_prolog(Params p) {
  __shared__ SMem sh;
  int u = blockIdx.x;
  if (u < 256) {
    gemm_tile64(p.h0, p.W_hh, p.gates0, G4, (u >> 5) * 64, (u & 31) * 64,
                u >> 5, &sh);
  } else {
    int i = (u - 256) * 256 + threadIdx.x;
    if (i < B * TX) p.acc0[i] = p.init_cov[i];
  }
}

// ---------------------------------------------------------------------------
// ONE kernel per step. Roles by blockIdx:
//   [0..511]   : attn unit (b,h) — cell(t) for b, hq slice, e, softmax,
//                coverage, pv-sum
//   [512..767] : gates(t+1) GEMM tile (computes its own h1 A-tile)
//   [768..831] : concat+LN of step t-1
// ---------------------------------------------------------------------------
__global__ __launch_bounds__(256) void k_step(Params p, int t) {
  __shared__ SMem sh;
  const int tid = threadIdx.x;
  const int u = blockIdx.x;
  const float* gates_cur = (t & 1) ? p.gates1 : p.gates0;
  float* gates_next      = (t & 1) ? p.gates0 : p.gates1;
  const float* acc_in    = (t & 1) ? p.acc1 : p.acc0;
  float* acc_out         = (t & 1) ? p.acc0 : p.acc1;
  float* attW            = (t & 1) ? p.att1 : p.att0;
  const float* attR      = (t & 1) ? p.att0 : p.att1;

  if (u < 512) {
    // ================= attention unit =================
    const int b = u >> 3, h = u & 7;
    const int wv = tid >> 6, lane = tid & 63;
    const float ym = p.y_mask[t * B + b];

    // ---- cell(t) for all 512 elements of batch row b (8x redundant) ----
    for (int m = tid; m < 512; m += 256) {
      float c1;
      float h1 = cell_elem(p, gates_cur, t, b, m, ym, c1);
      sh.u.at.xs[m] = h1;
      sh.u.at.xs[512 + m] = c1;
      if (h == 0) {
        p.hs[(size_t)t * B * H + b * H + m] = h1;
        p.ss[(size_t)t * B * H + b * H + m] = h1;
        p.cs[(size_t)t * B * H + b * H + m] = c1;
      }
    }
    __syncthreads();

    // ---- hq slice: hq[c] = sum_k xs[k] * W_comb[(h*64+c), k], c in [0,64) ----
    {
      int ci = tid >> 2, kq = tid & 3;
      const float* wr = p.W_comb + (size_t)(h * 64 + ci) * 1024 + kq * 256;
      const float* xk = sh.u.at.xs + kq * 256;
      float pq = 0.f;
      #pragma unroll
      for (int i = 0; i < 256; i += 4) {
        float4 w4 = *reinterpret_cast<const float4*>(&wr[i]);
        float4 x4 = *reinterpret_cast<const float4*>(&xk[i]);
        pq += x4.x * w4.x + x4.y * w4.y + x4.z * w4.z + x4.w * w4.w;
      }
      sh.u.at.hqp[kq][ci] = pq;
    }
    __syncthreads();
    if (tid < 64)
      sh.u.at.hqs[tid] = sh.u.at.hqp[0][tid] + sh.u.at.hqp[1][tid] +
                         sh.u.at.hqp[2][tid] + sh.u.at.hqp[3][tid];
    __syncthreads();

    // ---- e scores: lane = (sub=tt-subslot)<<4 | dq(c-quarter) ----
    const int sub = lane >> 4, dq = lane & 15;
    const float4 hq4 = *reinterpret_cast<const float4*>(&sh.u.at.hqs[dq * 4]);
    const float4 wc4 = *reinterpret_cast<const float4*>(&p.W_cov[h * 64 + dq * 4]);
    const float4 u4  = *reinterpret_cast<const float4*>(&p.U_att[h * 64 + dq * 4]);
    #pragma unroll 5
    for (int q = 0; q < 25; q++) {
      int tt = q * 16 + wv * 4 + sub;
      float a = acc_in[b * TX + tt];
      const float4 pc4 = *reinterpret_cast<const float4*>(
          &p.pctx[((size_t)(tt * B + b)) * C + h * 64 + dq * 4]);
      float v = tanhf(pc4.x + hq4.x + a * wc4.x) * u4.x +
                tanhf(pc4.y + hq4.y + a * wc4.y) * u4.y +
                tanhf(pc4.z + hq4.z + a * wc4.z) * u4.z +
                tanhf(pc4.w + hq4.w + a * wc4.w) * u4.w;
      v += __shfl_xor(v, 1);
      v += __shfl_xor(v, 2);
      v += __shfl_xor(v, 4);
      v += __shfl_xor(v, 8);
      float xm = p.x_mask[tt * B + b];
      if (dq == 0) sh.u.at.se[tt] = v * xm;
    }
    __syncthreads();

    // ---- softmax over 400 ----
    float e0 = (tid < TX) ? sh.u.at.se[tid] : -1e30f;
    float e1 = (tid + 256 < TX) ? sh.u.at.se[tid + 256] : -1e30f;
    float m = fmaxf(e0, e1);
    #pragma unroll
    for (int off = 32; off; off >>= 1) m = fmaxf(m, __shfl_xor(m, off));
    if (lane == 0) sh.u.at.sm[wv] = m;
    __syncthreads();
    m = fmaxf(fmaxf(sh.u.at.sm[0], sh.u.at.sm[1]),
              fmaxf(sh.u.at.sm[2], sh.u.at.sm[3]));
    float xm0 = (tid < TX) ? p.x_mask[tid * B + b] : 0.f;
    float xm1 = (tid + 256 < TX) ? p.x_mask[(tid + 256) * B + b] : 0.f;
    float w0 = (tid < TX) ? __expf(e0 - m) * xm0 : 0.f;
    float w1 = (tid + 256 < TX) ? __expf(e1 - m) * xm1 : 0.f;
    float s = w0 + w1;
    #pragma unroll
    for (int off = 32; off; off >>= 1) s += __shfl_xor(s, off);
    if (lane == 0) sh.u.at.ssum[wv] = s;
    __syncthreads();
    s = sh.u.at.ssum[0] + sh.u.at.ssum[1] + sh.u.at.ssum[2] +
        sh.u.at.ssum[3] + 1e-6f;
    float inv = 1.f / s;
    w0 *= inv; w1 *= inv;
    sh.u.at.wsh[tid] = w0;
    sh.u.at.wsh[tid + 256] = w1;
    if (h == 0) {
      float* dist_t = p.dists + (size_t)t * B * TX;
      float* Cs_t   = p.Cs + (size_t)t * B * TX;
      if (tid < TX) {
        float a = acc_in[b * TX + tid];
        dist_t[b * TX + tid] = w0;
        Cs_t[b * TX + tid] = a;
        acc_out[b * TX + tid] = a + w0;
      }
      if (tid + 256 < TX) {
        float a = acc_in[b * TX + tid + 256];
        dist_t[b * TX + tid + 256] = w1;
        Cs_t[b * TX + tid + 256] = a;
        acc_out[b * TX + tid + 256] = a + w1;
      }
    }
    __syncthreads();

    // ---- attention-weighted pv sum (float4, 25 iters) ----
    float4 a4 = make_float4(0.f, 0.f, 0.f, 0.f);
    #pragma unroll 5
    for (int q = 0; q < 25; q++) {
      int tt = q * 16 + wv * 4 + sub;
      float wgt = sh.u.at.wsh[tt];
      const float4 pv4 = *reinterpret_cast<const float4*>(
          &p.pv[((size_t)(tt * 64 + b) * 8 + h) * 64 + dq * 4]);
      a4.x += wgt * pv4.x;
      a4.y += wgt * pv4.y;
      a4.z += wgt * pv4.z;
      a4.w += wgt * pv4.w;
    }
    #pragma unroll
    for (int off = 16; off <= 32; off <<= 1) {
      a4.x += __shfl_xor(a4.x, off);
      a4.y += __shfl_xor(a4.y, off);
      a4.z += __shfl_xor(a4.z, off);
      a4.w += __shfl_xor(a4.w, off);
    }
    if (lane < 16)
      *reinterpret_cast<float4*>(&sh.u.at.pbuf[wv * 64 + dq * 4]) = a4;
    __syncthreads();
    if (tid < 64)
      attW[b * 512 + h * 64 + tid] =
          sh.u.at.pbuf[tid] + sh.u.at.pbuf[64 + tid] +
          sh.u.at.pbuf[128 + tid] + sh.u.at.pbuf[192 + tid];

  } else if (u < 768) {
    // ================= gates(t+1) GEMM tile =================
    if (t + 1 >= TY) return;
    const int g = u - 512;
    const int sliceIdx = g >> 5;
    const int kbeg = sliceIdx * 64;
    const int n0 = (g & 31) * 64;
    // compute own h1 A-tile [64 b][64 col] into LDS (masked h1)
    #pragma unroll
    for (int i = 0; i < 16; i++) {
      int idx = i * 256 + tid;
      int r = idx >> 6, kk = idx & 63;
      float ym = p.y_mask[t * B + r];
      float c1d;
      sh.u.g2.As64[r][kk] = cell_elem(p, gates_cur, t, r, kbeg + kk, ym, c1d);
    }
    __syncthreads();
    const int tx = tid & 15, ty = tid >> 4;
    float acc[4][4] = {};
    for (int kc = 0; kc < 4; kc++) {
      #pragma unroll
      for (int i = 0; i < 4; i++) {
        int idx = tid + i * 256;
        int r = idx >> 4, k = idx & 15;
        sh.u.g2.Ws[k][r] = p.W_hh[(size_t)(n0 + r) * 512 + kbeg + kc * 16 + k];
      }
      __syncthreads();
      #pragma unroll
      for (int k = 0; k < 16; k++) {
        float a[4], w[4];
        #pragma unroll
        for (int i = 0; i < 4; i++) a[i] = sh.u.g2.As64[ty * 4 + i][kc * 16 + k];
        #pragma unroll
        for (int j = 0; j < 4; j++) w[j] = sh.u.g2.Ws[k][tx * 4 + j];
        #pragma unroll
        for (int i = 0; i < 4; i++)
          #pragma unroll
          for (int j = 0; j < 4; j++) acc[i][j] += a[i] * w[j];
      }
      __syncthreads();
    }
    float* Pp = gates_next + (size_t)sliceIdx * 64 * G4;
    #pragma unroll
    for (int i = 0; i < 4; i++)
      #pragma unroll
      for (int j = 0; j < 4; j++)
        Pp[(size_t)(ty * 4 + i) * G4 + n0 + tx * 4 + j] = acc[i][j];

  } else {
    // ================= concat+LN of step t-1 =================
    if (t == 0) return;
    concat_block(u - 768, attR, p.W_cat, p.ln_g, p.ln_b,
                 p.atts + (size_t)(t - 1) * B * C, &sh);
  }
}

// Epilogue: concat+LN of final step, 64 blocks
__global__ __launch_bounds__(256) void k_epilog(Params p) {
  __shared__ SMem sh;
  const float* attR = ((TY - 1) & 1) ? p.att1 : p.att0;
  concat_block(blockIdx.x, attR, p.W_cat, p.ln_g, p.ln_b,
               p.atts + (size_t)(TY - 1) * B * C, &sh);
}

// ---------------------------------------------------------------------------
extern "C" void kernel_launch(void* const* d_in, const int* in_sizes, int n_in,
                              void* d_out, int out_size, void* d_ws, size_t ws_size,
                              hipStream_t stream) {
  const float* y_emb    = (const float*)d_in[0];
  const float* context  = (const float*)d_in[1];
  const float* h0       = (const float*)d_in[2];
  const float* c0       = (const float*)d_in[3];
  const float* x_mask   = (const float*)d_in[4];
  const float* y_mask   = (const float*)d_in[5];
  const float* init_cov = (const float*)d_in[6];
  const float* W_ih     = (const float*)d_in[7];
  const float* W_hh     = (const float*)d_in[8];
  const float* b_ih     = (const float*)d_in[9];
  const float* b_hh     = (const float*)d_in[10];
  const float* Wc_att   = (const float*)d_in[11];
  const float* b_att    = (const float*)d_in[12];
  const float* Wv_att   = (const float*)d_in[13];
  const float* bv_att   = (const float*)d_in[14];
  const float* W_comb   = (const float*)d_in[15];
  const float* U_att    = (const float*)d_in[16];
  const float* W_cov    = (const float*)d_in[17];
  const float* W_cat    = (const float*)d_in[18];
  const float* ln_g     = (const float*)d_in[19];
  const float* ln_b     = (const float*)d_in[20];

  float* out = (float*)d_out;
  const size_t SZ_H = (size_t)TY * B * H;
  const size_t SZ_D = (size_t)TY * B * TX;
  float* hs    = out;
  float* cs    = out + SZ_H;
  float* ss    = out + 2 * SZ_H;
  float* atts  = out + 3 * SZ_H;
  float* dists = out + 4 * SZ_H;
  float* Cs    = out + 4 * SZ_H + SZ_D;

  float* ws = (float*)d_ws;
  size_t off = 0;
  float* pctx   = ws + off; off += (size_t)TX * B * C;
  float* pv     = ws + off; off += (size_t)TX * B * C;
  float* xW     = ws + off; off += (size_t)TY * B * G4;
  float* gates0 = ws + off; off += (size_t)8 * B * G4;
  float* gates1 = ws + off; off += (size_t)8 * B * G4;
  float* att0   = ws + off; off += (size_t)B * C;
  float* att1   = ws + off; off += (size_t)B * C;
  float* acc0   = ws + off; off += (size_t)B * TX;
  float* acc1   = ws + off; off += (size_t)B * TX;

  // ---- precompute (big parallel GEMMs) ----
  gemm_bias<<<dim3(C / 64, TX * B / 64), 256, 0, stream>>>(
      context, Wc_att, b_att, nullptr, pctx, C, C);
  gemm_bias<<<dim3(C / 64, TX * B / 64), 256, 0, stream>>>(
      context, Wv_att, bv_att, nullptr, pv, C, C);
  gemm_bias<<<dim3(G4 / 64, TY * B / 64), 256, 0, stream>>>(
      y_emb, W_ih, b_ih, b_hh, xW, G4, IN);

  Params prm;
  prm.h0 = h0; prm.c0 = c0; prm.x_mask = x_mask; prm.y_mask = y_mask;
  prm.init_cov = init_cov;
  prm.W_hh = W_hh; prm.W_comb = W_comb; prm.U_att = U_att; prm.W_cov = W_cov;
  prm.W_cat = W_cat; prm.ln_g = ln_g; prm.ln_b = ln_b;
  prm.xW = xW; prm.pctx = pctx; prm.pv = pv;
  prm.gates0 = gates0; prm.gates1 = gates1;
  prm.att0 = att0; prm.att1 = att1;
  prm.acc0 = acc0; prm.acc1 = acc1;
  prm.hs = hs; prm.cs = cs; prm.ss = ss;
  prm.atts = atts; prm.dists = dists; prm.Cs = Cs;

  // ---- prologue: gates(0) + coverage init ----
  k_prolog<<<356, 256, 0, stream>>>(prm);

  // ---- ONE launch per step ----
  for (int t = 0; t < TY; t++)
    k_step<<<832, 256, 0, stream>>>(prm, t);

  k_epilog<<<64, 256, 0, stream>>>(prm);
}